// Round 13
// baseline (131.939 us; speedup 1.0000x reference)
//
#include <hip/hip_runtime.h>

// out[N,32] = segment_sum(edge_val[e] * weight[edge_col[e], :], edge_row[e]) + bias
//
// v12: v8's partition + COLUMN-ZONED accumulate with XCD affinity.
//   The measured wall: accum's 1.6M random 128B weight-line requests run at
//   ~2.5-3 TB/s = XCD L2-miss fill rate (weight 12.8MB >> 4MB L2, ~15% hit).
//   Fix: 4 column zones of N/4 cols (~3.2MB weight slice, fits one XCD's L2).
//   gnn_accum_z: WG per (bucket, zone), bid = bucket*4+zone. XCD = bid%8 ->
//   XCD x only touches zone x%4's slice -> weight L2-resident. Each zone-WG
//   filters its bucket's records by col zone, row-sorts in LDS, register-
//   gathers (4 float4 lines in flight), writes a partial[zone] slab (no bias).
//   gnn_reduce: out[r] = sum_z partial[z][r] + bias (+ exact spill merge).
//
// Fallbacks: v2 bin+gather if ws too small / shape out of range; v0 atomics last.

#define FEAT 32
#define LOG_RPB 7
#define RPB (1 << LOG_RPB)
#define COLBITS 17
#define CMASK ((1u << COLBITS) - 1)
#define BMAX 1024
#define PCHUNK 4096
#define PTHREADS 1024
#define EPT (PCHUNK / PTHREADS)      // 4 edges per thread
#define CAPB 2560                    // record slots per bucket
#define CAPZ 1024                    // per-(bucket,zone) LDS capacity (mean 512)
#define CAP_MAX 32

// ---------------- v12 kernels ----------------

__global__ __launch_bounds__(256) void gnn_zero(
    int* __restrict__ cursor, int* __restrict__ scnt, int B) {
    int i = blockIdx.x * 256 + threadIdx.x;
    if (i < B) cursor[i] = 0;
    if (i == B) *scnt = 0;
}

__global__ __launch_bounds__(PTHREADS) void gnn_part(
    const int* __restrict__ edge_row,
    const int* __restrict__ edge_col,
    const float* __restrict__ edge_val,
    int* __restrict__ cursor,
    float2* __restrict__ parts,
    float4* __restrict__ spill,
    int* __restrict__ scnt,
    int num_edges, int B) {
    __shared__ float2 lrec[PCHUNK];              // 32 KB
    __shared__ unsigned short lbkt[PCHUNK];      // 8 KB
    __shared__ int hcur[BMAX];
    __shared__ int st[BMAX];
    __shared__ int wtot[16], wbase[16];
    int t = threadIdx.x;
    hcur[t] = 0;
    __syncthreads();

    int e0 = blockIdx.x * PCHUNK;
    int cnt_chunk = num_edges - e0;
    if (cnt_chunk > PCHUNK) cnt_chunk = PCHUNK;

    int  r[EPT], c[EPT], bb[EPT], slot[EPT];
    float vv[EPT];
    int ebase = e0 + 4 * t;
    if (ebase + 3 < num_edges) {
        int4  r4 = *(const int4*)(edge_row + ebase);
        int4  c4 = *(const int4*)(edge_col + ebase);
        float4 v4 = *(const float4*)(edge_val + ebase);
        r[0]=r4.x; r[1]=r4.y; r[2]=r4.z; r[3]=r4.w;
        c[0]=c4.x; c[1]=c4.y; c[2]=c4.z; c[3]=c4.w;
        vv[0]=v4.x; vv[1]=v4.y; vv[2]=v4.z; vv[3]=v4.w;
    } else {
        #pragma unroll
        for (int k = 0; k < EPT; ++k) {
            int e = ebase + k;
            bool ok = e < num_edges;
            r[k]  = ok ? edge_row[e] : -1;
            c[k]  = ok ? edge_col[e] : 0;
            vv[k] = ok ? edge_val[e] : 0.f;
        }
    }
    #pragma unroll
    for (int k = 0; k < EPT; ++k) {
        if (r[k] >= 0) {
            bb[k] = r[k] >> LOG_RPB;
            slot[k] = atomicAdd(&hcur[bb[k]], 1);
        }
    }
    __syncthreads();

    int v = hcur[t];
    int wid = t >> 6, lane = t & 63;
    int x = v;
    #pragma unroll
    for (int off = 1; off < 64; off <<= 1) {
        int y = __shfl_up(x, off);
        if (lane >= off) x += y;
    }
    if (lane == 63) wtot[wid] = x;
    __syncthreads();
    if (t < 16) {
        int w = wtot[t], xx = w;
        #pragma unroll
        for (int off = 1; off < 16; off <<= 1) {
            int y = __shfl_up(xx, off);
            if (t >= off) xx += y;
        }
        wbase[t] = xx - w;
    }
    __syncthreads();
    int ex = x - v + wbase[wid];
    st[t] = ex;
    int rbase = 0;
    if (t < B && v) rbase = atomicAdd(&cursor[t], v);
    hcur[t] = rbase;
    __syncthreads();

    #pragma unroll
    for (int k = 0; k < EPT; ++k) {
        if (r[k] >= 0) {
            int pos = st[bb[k]] + slot[k];
            unsigned pk = (unsigned)c[k] |
                          ((unsigned)(r[k] & (RPB - 1)) << COLBITS);
            lrec[pos] = make_float2(__uint_as_float(pk), vv[k]);
            lbkt[pos] = (unsigned short)bb[k];
        }
    }
    __syncthreads();

    for (int i = t; i < cnt_chunk; i += PTHREADS) {
        int b2 = lbkt[i];
        float2 rec = lrec[i];
        int s = hcur[b2] + (i - st[b2]);
        if (s < CAPB) {
            parts[(long long)b2 * CAPB + s] = rec;
        } else {
            int si = atomicAdd(scnt, 1);
            unsigned pk = __float_as_uint(rec.x);
            spill[si] = make_float4(
                __uint_as_float((unsigned)(b2 << LOG_RPB) + (pk >> COLBITS)),
                __uint_as_float(pk & CMASK), rec.y, 0.f);
        }
    }
}

// bid = bucket*4 + zone; XCD = bid%8 -> XCD x only handles zone x%4.
__global__ __launch_bounds__(512) void gnn_accum_z(
    const float2* __restrict__ parts,
    const int* __restrict__ cursor,
    const float* __restrict__ weight,
    float* __restrict__ partial,
    float4* __restrict__ spill,
    int* __restrict__ scnt,
    int n_nodes, int z1, int z2, int z3) {
    __shared__ float2 srec[CAPZ];       // 8 KB: zone-filtered, row-sorted
    __shared__ int h[RPB];
    __shared__ int rs[RPB + 1];
    int bid = blockIdx.x, t = threadIdx.x;
    int zone = bid & 3;
    int b = bid >> 2;
    int n = cursor[b];
    int m = n < CAPB ? n : CAPB;
    const float2* p = parts + (long long)b * CAPB;
    int row0 = b << LOG_RPB;

    // 1) coalesced load + zone filter + fused row hist/slot
    float2 rec[CAPB / 512];
    int rl[CAPB / 512], slot[CAPB / 512];
    bool keep[CAPB / 512];
    if (t < RPB) h[t] = 0;
    __syncthreads();
    #pragma unroll
    for (int k = 0; k < CAPB / 512; ++k) {
        int idx = t + k * 512;
        bool ok = idx < m;
        rec[k] = ok ? p[idx] : make_float2(0.f, 0.f);
        unsigned pk = __float_as_uint(rec[k].x);
        int c = (int)(pk & CMASK);
        int zz = (c >= z1) + (c >= z2) + (c >= z3);
        keep[k] = ok && (zz == zone);
        if (keep[k]) {
            rl[k] = (int)((pk >> COLBITS) & (RPB - 1));
            slot[k] = atomicAdd(&h[rl[k]], 1);
        }
    }
    __syncthreads();

    // 2) wave-0 scan of 128 row counts
    if (t < 64) {
        int a  = h[2 * t];
        int c2 = h[2 * t + 1];
        int pr = a + c2;
        int x = pr;
        #pragma unroll
        for (int off = 1; off < 64; off <<= 1) {
            int y = __shfl_up(x, off);
            if (t >= off) x += y;
        }
        int exc = x - pr;
        rs[2 * t] = exc;
        rs[2 * t + 1] = exc + a;
        if (t == 63) rs[RPB] = x;
    }
    __syncthreads();

    // 3) scatter -> row-sorted LDS (guard CAPZ; excess -> exact spill)
    #pragma unroll
    for (int k = 0; k < CAPB / 512; ++k) {
        if (keep[k]) {
            int pos = rs[rl[k]] + slot[k];
            if (pos < CAPZ) {
                srec[pos] = rec[k];
            } else {
                int si = atomicAdd(scnt, 1);
                unsigned pk = __float_as_uint(rec[k].x);
                spill[si] = make_float4(
                    __uint_as_float((unsigned)(row0 + rl[k])),
                    __uint_as_float(pk & CMASK), rec[k].y, 0.f);
            }
        }
    }
    __syncthreads();

    // 4) register gather (weight slice is XCD-L2-resident), 4 lines in flight
    int g = t >> 3;                     // 64 groups of 8 lanes
    int l = t & 7;
    #pragma unroll 1
    for (int rr = 0; rr < 2; ++rr) {
        int rlc = (g << 1) + rr;
        int s = rs[rlc], e = rs[rlc + 1];
        if (s > CAPZ) s = CAPZ;
        if (e > CAPZ) e = CAPZ;
        float4 acc = make_float4(0.f, 0.f, 0.f, 0.f);
        for (int j = s; j < e; j += 4) {
            unsigned pk[4]; float vvv[4];
            #pragma unroll
            for (int k = 0; k < 4; ++k) {
                int jj = j + k;
                float2 rc = srec[jj < e ? jj : s];
                pk[k] = __float_as_uint(rc.x);
                vvv[k] = rc.y;
            }
            float4 w4[4];
            #pragma unroll
            for (int k = 0; k < 4; ++k)
                w4[k] = *(const float4*)(
                    weight + (long long)(pk[k] & CMASK) * FEAT + (l << 2));
            #pragma unroll
            for (int k = 0; k < 4; ++k) {
                float sc = (j + k < e) ? vvv[k] : 0.f;
                acc.x += sc * w4[k].x;
                acc.y += sc * w4[k].y;
                acc.z += sc * w4[k].z;
                acc.w += sc * w4[k].w;
            }
        }
        int rrow = row0 + rlc;
        if (rrow < n_nodes)
            *(float4*)(partial + ((long long)zone * n_nodes + rrow) * FEAT +
                       (l << 2)) = acc;
    }
}

__global__ __launch_bounds__(256) void gnn_reduce(
    const float* __restrict__ partial,
    const int* __restrict__ scnt,
    const float4* __restrict__ spill,
    const float* __restrict__ weight,
    const float* __restrict__ bias,
    float* __restrict__ out,
    int n_nodes) {
    int gid = (blockIdx.x * 256 + threadIdx.x) >> 3;   // row
    if (gid >= n_nodes) return;
    int l = threadIdx.x & 7;
    float4 a = make_float4(0.f, 0.f, 0.f, 0.f);
    #pragma unroll
    for (int z = 0; z < 4; ++z) {
        float4 q = *(const float4*)(
            partial + ((long long)z * n_nodes + gid) * FEAT + (l << 2));
        a.x += q.x; a.y += q.y; a.z += q.z; a.w += q.w;
    }
    int ns = *scnt;
    if (ns > 0) {                      // exact, never taken for uniform data
        for (int i = 0; i < ns; ++i) {
            float4 sp = spill[i];
            if ((int)__float_as_uint(sp.x) == gid) {
                const float4 wz = *(const float4*)(
                    weight + (long long)__float_as_uint(sp.y) * FEAT + (l << 2));
                a.x += sp.z * wz.x;
                a.y += sp.z * wz.y;
                a.z += sp.z * wz.z;
                a.w += sp.z * wz.w;
            }
        }
    }
    float4 bf4 = ((const float4*)bias)[l];
    float4 o = make_float4(a.x + bf4.x, a.y + bf4.y, a.z + bf4.z, a.w + bf4.w);
    *(float4*)(out + (long long)gid * FEAT + (l << 2)) = o;
}

// ---------------- v2 fallback (bin + gather) ----------------

__global__ __launch_bounds__(256) void gnn_init(
    const float* __restrict__ bias, float* __restrict__ out,
    int* __restrict__ cnt, int total4, int n_nodes) {
    int i = blockIdx.x * blockDim.x + threadIdx.x;
    if (i < total4) {
        float4 bb = ((const float4*)bias)[i & 7];
        ((float4*)out)[i] = bb;
    }
    if (i < n_nodes) cnt[i] = 0;
}

__global__ __launch_bounds__(256) void gnn_bin(
    const int* __restrict__ edge_row,
    const int* __restrict__ edge_col,
    const float* __restrict__ edge_val,
    const float* __restrict__ weight,
    float2* __restrict__ bins,
    int* __restrict__ cnt,
    float* __restrict__ out,
    int num_edges, int cap) {
    int e = blockIdx.x * blockDim.x + threadIdx.x;
    if (e >= num_edges) return;
    int r = edge_row[e];
    int c = edge_col[e];
    float v = edge_val[e];
    int slot = atomicAdd(&cnt[r], 1);
    if (slot < cap) {
        bins[(long long)r * cap + slot] = make_float2(__int_as_float(c), v);
    } else {
        const float* w = weight + (long long)c * FEAT;
        #pragma unroll
        for (int f = 0; f < FEAT; ++f)
            atomicAdd(out + (long long)r * FEAT + f, v * w[f]);
    }
}

__global__ __launch_bounds__(256) void gnn_gather(
    const float2* __restrict__ bins,
    const int* __restrict__ cnt,
    const float* __restrict__ weight,
    float* __restrict__ out,
    int n_nodes, int cap) {
    int g = (blockIdx.x * blockDim.x + threadIdx.x) >> 5;
    int f = threadIdx.x & (FEAT - 1);
    if (g >= n_nodes) return;
    int n = cnt[g];
    n = n < cap ? n : cap;
    const float2* b = bins + (long long)g * cap;
    float a0 = 0.f, a1 = 0.f, a2 = 0.f, a3 = 0.f;
    int j = 0;
    for (; j + 4 <= n; j += 4) {
        float2 e0 = b[j], e1 = b[j + 1], e2 = b[j + 2], e3 = b[j + 3];
        a0 += e0.y * weight[(long long)__float_as_int(e0.x) * FEAT + f];
        a1 += e1.y * weight[(long long)__float_as_int(e1.x) * FEAT + f];
        a2 += e2.y * weight[(long long)__float_as_int(e2.x) * FEAT + f];
        a3 += e3.y * weight[(long long)__float_as_int(e3.x) * FEAT + f];
    }
    for (; j < n; ++j) {
        float2 e0 = b[j];
        a0 += e0.y * weight[(long long)__float_as_int(e0.x) * FEAT + f];
    }
    out[(long long)g * FEAT + f] += (a0 + a1) + (a2 + a3);
}

// ---------------- v0 fallback ----------------

__global__ __launch_bounds__(256) void gnn_init_out(
    const float* __restrict__ bias, float* __restrict__ out, int total) {
    int i = blockIdx.x * blockDim.x + threadIdx.x;
    if (i < total) out[i] = bias[i & (FEAT - 1)];
}

__global__ __launch_bounds__(256) void gnn_scatter(
    const int* __restrict__ edge_row,
    const int* __restrict__ edge_col,
    const float* __restrict__ edge_val,
    const float* __restrict__ weight,
    float* __restrict__ out,
    int num_edges) {
    long long t = (long long)blockIdx.x * blockDim.x + threadIdx.x;
    int e = (int)(t >> 5);
    int f = (int)(t & (FEAT - 1));
    if (e < num_edges) {
        int r = edge_row[e];
        int c = edge_col[e];
        atomicAdd(out + r * FEAT + f, edge_val[e] * weight[c * FEAT + f]);
    }
}

extern "C" void kernel_launch(void* const* d_in, const int* in_sizes, int n_in,
                              void* d_out, int out_size, void* d_ws, size_t ws_size,
                              hipStream_t stream) {
    const int*   edge_row = (const int*)d_in[0];
    const int*   edge_col = (const int*)d_in[1];
    const float* edge_val = (const float*)d_in[2];
    const float* weight   = (const float*)d_in[3];
    const float* bias     = (const float*)d_in[4];
    float* out = (float*)d_out;

    const int E = in_sizes[0];
    const int total = out_size;        // N * 32 elements
    const int N = total / FEAT;
    const int B = (N + RPB - 1) >> LOG_RPB;

    auto align256 = [](size_t x) { return (x + 255) & ~(size_t)255; };
    size_t cursor_off  = 0;
    size_t scnt_off    = align256(cursor_off + (size_t)B * sizeof(int));
    size_t spill_off   = align256(scnt_off + sizeof(int));
    size_t parts_off   = align256(spill_off + (size_t)E * sizeof(float4));
    size_t partial_off = align256(parts_off + (size_t)B * CAPB * sizeof(float2));
    size_t need_v12    = partial_off + 4ull * N * FEAT * sizeof(float);

    if (B >= 1 && B <= BMAX && N <= (1 << COLBITS) && E > 0 &&
        ws_size >= need_v12) {
        int*    cursor  = (int*)((char*)d_ws + cursor_off);
        int*    scnt    = (int*)((char*)d_ws + scnt_off);
        float4* spill   = (float4*)((char*)d_ws + spill_off);
        float2* parts   = (float2*)((char*)d_ws + parts_off);
        float*  partial = (float*)((char*)d_ws + partial_off);

        int zdiv = (N + 3) / 4;
        int z1 = zdiv, z2 = 2 * zdiv, z3 = 3 * zdiv;

        gnn_zero<<<(B + 1 + 255) / 256, 256, 0, stream>>>(cursor, scnt, B);
        gnn_part<<<(E + PCHUNK - 1) / PCHUNK, PTHREADS, 0, stream>>>(
            edge_row, edge_col, edge_val, cursor, parts, spill, scnt, E, B);
        gnn_accum_z<<<B * 4, 512, 0, stream>>>(
            parts, cursor, weight, partial, spill, scnt, N, z1, z2, z3);
        long long rthreads = (long long)N * 8;
        gnn_reduce<<<(int)((rthreads + 255) / 256), 256, 0, stream>>>(
            partial, scnt, spill, weight, bias, out, N);
        return;
    }

    // v2 fallback: bin + gather
    size_t cnt_bytes = align256((size_t)N * sizeof(int));
    long long cap_ll = 0;
    if (ws_size > cnt_bytes)
        cap_ll = (long long)((ws_size - cnt_bytes) / ((size_t)N * sizeof(float2)));
    int cap = (int)(cap_ll > CAP_MAX ? CAP_MAX : cap_ll);

    if (cap >= 16) {
        int* cnt = (int*)d_ws;
        float2* bins = (float2*)((char*)d_ws + cnt_bytes);
        int total4 = total / 4;
        int init_threads = total4 > N ? total4 : N;
        gnn_init<<<(init_threads + 255) / 256, 256, 0, stream>>>(
            bias, out, cnt, total4, N);
        gnn_bin<<<(E + 255) / 256, 256, 0, stream>>>(
            edge_row, edge_col, edge_val, weight, bins, cnt, out, E, cap);
        long long gthreads = (long long)N * FEAT;
        gnn_gather<<<(int)((gthreads + 255) / 256), 256, 0, stream>>>(
            bins, cnt, weight, out, N, cap);
    } else {
        gnn_init_out<<<(total + 255) / 256, 256, 0, stream>>>(bias, out, total);
        long long threads = (long long)E * FEAT;
        gnn_scatter<<<(int)((threads + 255) / 256), 256, 0, stream>>>(
            edge_row, edge_col, edge_val, weight, out, E);
    }
}

// Round 14
// 120.567 us; speedup vs baseline: 1.0943x; 1.0943x over previous
//
#include <hip/hip_runtime.h>

// out[N,32] = segment_sum(edge_val[e] * weight[edge_col[e], :], edge_row[e]) + bias
//
// v13 = v8 restored (measured best: 122.1us). Fused 3-kernel structure:
//   K0 gnn_zero : cursor[B]=0, scnt=0
//   K1 gnn_part : per 4096-edge chunk: vector edge loads, fused hist+slot,
//                 wave scan, global run reservation, LDS bucket-order scatter
//                 (no atomics), coalesced writeout; overflow -> exact spill.
//   K2 gnn_accum: per bucket (512 thr): regs load, fused row hist+slot, wave
//                 scan, LDS row-sort scatter (no atomics), 64 groups x 8 lanes
//                 register-gather w/ float4 (8 weight lines in flight),
//                 spill merge, coalesced store (+bias).
//
// Structural ceiling evidence (v7..v12 all 122-134us):
//   - gather: 1.6M random 128B weight lines = 205MB at ~2.7-3 TB/s measured
//     random-line rate (streaming reaches 6.3 TB/s on this machine). No
//     over-fetch (all 128B consumed); reuse not exploitable without col-sort,
//     which moves the permutation onto 128B contributions (worse).
//   - partition: ~40us, sticky under run-lengthening (v11) and atomic/barrier
//     removal (v7): store-issue granularity on a scattered 8B stream.
//
// Fallbacks: v2 bin+gather if ws too small / shape out of range; v0 atomics last.

#define FEAT 32
#define LOG_RPB 7
#define RPB (1 << LOG_RPB)
#define COLBITS 17
#define CMASK ((1u << COLBITS) - 1)
#define BMAX 1024
#define PCHUNK 4096
#define PTHREADS 1024
#define EPT (PCHUNK / PTHREADS)      // 4 edges per thread
#define CAPB 2560                    // record slots per bucket (mult of 512)
#define CAP_MAX 32

// ---------------- v13 (= v8) kernels ----------------

__global__ __launch_bounds__(256) void gnn_zero(
    int* __restrict__ cursor, int* __restrict__ scnt, int B) {
    int i = blockIdx.x * 256 + threadIdx.x;
    if (i < B) cursor[i] = 0;
    if (i == B) *scnt = 0;
}

__global__ __launch_bounds__(PTHREADS) void gnn_part(
    const int* __restrict__ edge_row,
    const int* __restrict__ edge_col,
    const float* __restrict__ edge_val,
    int* __restrict__ cursor,
    float2* __restrict__ parts,
    float4* __restrict__ spill,
    int* __restrict__ scnt,
    int num_edges, int B) {
    __shared__ float2 lrec[PCHUNK];              // 32 KB
    __shared__ unsigned short lbkt[PCHUNK];      // 8 KB
    __shared__ int hcur[BMAX];                   // hist+slots, then run base
    __shared__ int st[BMAX];                     // exclusive starts
    __shared__ int wtot[16], wbase[16];
    int t = threadIdx.x;
    hcur[t] = 0;
    __syncthreads();

    int e0 = blockIdx.x * PCHUNK;
    int cnt_chunk = num_edges - e0;
    if (cnt_chunk > PCHUNK) cnt_chunk = PCHUNK;

    // 1) vectorized edge loads + fused histogram/slot assignment
    int  r[EPT], c[EPT], bb[EPT], slot[EPT];
    float vv[EPT];
    int ebase = e0 + 4 * t;
    if (ebase + 3 < num_edges) {
        int4  r4 = *(const int4*)(edge_row + ebase);
        int4  c4 = *(const int4*)(edge_col + ebase);
        float4 v4 = *(const float4*)(edge_val + ebase);
        r[0] = r4.x; r[1] = r4.y; r[2] = r4.z; r[3] = r4.w;
        c[0] = c4.x; c[1] = c4.y; c[2] = c4.z; c[3] = c4.w;
        vv[0] = v4.x; vv[1] = v4.y; vv[2] = v4.z; vv[3] = v4.w;
    } else {
        #pragma unroll
        for (int k = 0; k < EPT; ++k) {
            int e = ebase + k;
            bool ok = e < num_edges;
            r[k]  = ok ? edge_row[e] : -1;
            c[k]  = ok ? edge_col[e] : 0;
            vv[k] = ok ? edge_val[e] : 0.f;
        }
    }
    #pragma unroll
    for (int k = 0; k < EPT; ++k) {
        if (r[k] >= 0) {
            bb[k] = r[k] >> LOG_RPB;
            slot[k] = atomicAdd(&hcur[bb[k]], 1);   // rank within bucket
        }
    }
    __syncthreads();

    // 2) two-level shfl scan of counts (3 barriers) + global run reservation
    int v = hcur[t];
    int wid = t >> 6, lane = t & 63;
    int x = v;
    #pragma unroll
    for (int off = 1; off < 64; off <<= 1) {
        int y = __shfl_up(x, off);
        if (lane >= off) x += y;
    }
    if (lane == 63) wtot[wid] = x;
    __syncthreads();
    if (t < 16) {
        int w = wtot[t], xx = w;
        #pragma unroll
        for (int off = 1; off < 16; off <<= 1) {
            int y = __shfl_up(xx, off);
            if (t >= off) xx += y;
        }
        wbase[t] = xx - w;
    }
    __syncthreads();
    int ex = x - v + wbase[wid];                 // exclusive start
    st[t] = ex;
    int rbase = 0;
    if (t < B && v) rbase = atomicAdd(&cursor[t], v);
    hcur[t] = rbase;                             // reuse as global run base
    __syncthreads();

    // 3) scatter into LDS in bucket order — NO atomics (slot known)
    #pragma unroll
    for (int k = 0; k < EPT; ++k) {
        if (r[k] >= 0) {
            int pos = st[bb[k]] + slot[k];
            unsigned pk = (unsigned)c[k] |
                          ((unsigned)(r[k] & (RPB - 1)) << COLBITS);
            lrec[pos] = make_float2(__uint_as_float(pk), vv[k]);
            lbkt[pos] = (unsigned short)bb[k];
        }
    }
    __syncthreads();

    // 4) coalesced writeout (consecutive i -> consecutive slots of one bucket)
    for (int i = t; i < cnt_chunk; i += PTHREADS) {
        int b2 = lbkt[i];
        float2 rec = lrec[i];
        int s = hcur[b2] + (i - st[b2]);
        if (s < CAPB) {
            parts[(long long)b2 * CAPB + s] = rec;
        } else {
            // exact overflow path (never taken for uniform data)
            int si = atomicAdd(scnt, 1);
            unsigned pk = __float_as_uint(rec.x);
            spill[si] = make_float4(
                __uint_as_float((unsigned)(b2 << LOG_RPB) + (pk >> COLBITS)),
                __uint_as_float(pk & CMASK), rec.y, 0.f);
        }
    }
}

__global__ __launch_bounds__(512) void gnn_accum(
    const float2* __restrict__ parts,
    const int* __restrict__ cursor,
    const int* __restrict__ scnt,
    const float4* __restrict__ spill,
    const float* __restrict__ weight,
    const float* __restrict__ bias,
    float* __restrict__ out,
    int n_nodes) {
    __shared__ float2 srec[CAPB];       // 20 KB: row-sorted records
    __shared__ int h[RPB];
    __shared__ int rs[RPB + 1];
    int b = blockIdx.x, t = threadIdx.x;
    int n = cursor[b];
    int nspill = *scnt;                 // uniform; 0 in the common case
    int m = n < CAPB ? n : CAPB;
    const float2* p = parts + (long long)b * CAPB;

    // 1) load records to registers + fused row histogram/slot
    float2 rec[CAPB / 512];
    int rl[CAPB / 512], slot[CAPB / 512];
    if (t < RPB) h[t] = 0;
    __syncthreads();
    #pragma unroll
    for (int k = 0; k < CAPB / 512; ++k) {
        int idx = t + k * 512;
        bool ok = idx < m;
        rec[k] = ok ? p[idx] : make_float2(0.f, 0.f);
        if (ok) {
            rl[k] = (int)((__float_as_uint(rec[k].x) >> COLBITS) & (RPB - 1));
            slot[k] = atomicAdd(&h[rl[k]], 1);     // rank within row
        }
    }
    __syncthreads();

    // 2) wave-0 scan of 128 row counts via shfl (2 elems/lane)
    if (t < 64) {
        int a  = h[2 * t];
        int c2 = h[2 * t + 1];
        int pr = a + c2;
        int x = pr;
        #pragma unroll
        for (int off = 1; off < 64; off <<= 1) {
            int y = __shfl_up(x, off);
            if (t >= off) x += y;
        }
        int exc = x - pr;
        rs[2 * t] = exc;
        rs[2 * t + 1] = exc + a;
        if (t == 63) rs[RPB] = x;
    }
    __syncthreads();

    // 3) scatter registers -> row-sorted LDS — NO atomics
    #pragma unroll
    for (int k = 0; k < CAPB / 512; ++k) {
        int idx = t + k * 512;
        if (idx < m) srec[rs[rl[k]] + slot[k]] = rec[k];
    }
    __syncthreads();

    // 4) register-accumulate gather: 64 groups of 8 lanes; group owns 2 rows.
    //    Lane l loads weight[col][4l..4l+3] (float4): one wave load instruction
    //    fetches 8 records' 128B lines; 8-deep unroll -> 64 lines in flight.
    int g = t >> 3;                     // 64 groups
    int l = t & 7;
    int row0 = b << LOG_RPB;
    float4 bf4 = ((const float4*)bias)[l];
    #pragma unroll 1
    for (int rr = 0; rr < 2; ++rr) {
        int rlc = (g << 1) + rr;
        int s = rs[rlc], e = rs[rlc + 1];
        float4 acc = make_float4(0.f, 0.f, 0.f, 0.f);
        for (int j = s; j < e; j += 8) {
            unsigned pk[8]; float vv[8];
            #pragma unroll
            for (int k = 0; k < 8; ++k) {
                int jj = j + k;
                float2 rc = srec[jj < e ? jj : s];      // broadcast LDS read
                pk[k] = __float_as_uint(rc.x);
                vv[k] = rc.y;
            }
            float4 w4[8];
            #pragma unroll
            for (int k = 0; k < 8; ++k)
                w4[k] = *(const float4*)(
                    weight + (long long)(pk[k] & CMASK) * FEAT + (l << 2));
            #pragma unroll
            for (int k = 0; k < 8; ++k) {
                float sc = (j + k < e) ? vv[k] : 0.f;
                acc.x += sc * w4[k].x;
                acc.y += sc * w4[k].y;
                acc.z += sc * w4[k].z;
                acc.w += sc * w4[k].w;
            }
        }
        // merge rare spill entries for this row (nspill==0 normally)
        if (nspill > 0) {
            for (int i = 0; i < nspill; ++i) {
                float4 sp = spill[i];
                if ((int)__float_as_uint(sp.x) == row0 + rlc) {
                    float4 wz = *(const float4*)(
                        weight + (long long)__float_as_uint(sp.y) * FEAT +
                        (l << 2));
                    acc.x += sp.z * wz.x;
                    acc.y += sp.z * wz.y;
                    acc.z += sp.z * wz.z;
                    acc.w += sp.z * wz.w;
                }
            }
        }
        int rrow = row0 + rlc;
        if (rrow < n_nodes) {
            float4 o = make_float4(acc.x + bf4.x, acc.y + bf4.y,
                                   acc.z + bf4.z, acc.w + bf4.w);
            *(float4*)(out + (long long)rrow * FEAT + (l << 2)) = o;
        }
    }
}

// ---------------- v2 fallback (bin + gather) ----------------

__global__ __launch_bounds__(256) void gnn_init(
    const float* __restrict__ bias, float* __restrict__ out,
    int* __restrict__ cnt, int total4, int n_nodes) {
    int i = blockIdx.x * blockDim.x + threadIdx.x;
    if (i < total4) {
        float4 bb = ((const float4*)bias)[i & 7];
        ((float4*)out)[i] = bb;
    }
    if (i < n_nodes) cnt[i] = 0;
}

__global__ __launch_bounds__(256) void gnn_bin(
    const int* __restrict__ edge_row,
    const int* __restrict__ edge_col,
    const float* __restrict__ edge_val,
    const float* __restrict__ weight,
    float2* __restrict__ bins,
    int* __restrict__ cnt,
    float* __restrict__ out,
    int num_edges, int cap) {
    int e = blockIdx.x * blockDim.x + threadIdx.x;
    if (e >= num_edges) return;
    int r = edge_row[e];
    int c = edge_col[e];
    float v = edge_val[e];
    int slot = atomicAdd(&cnt[r], 1);
    if (slot < cap) {
        bins[(long long)r * cap + slot] = make_float2(__int_as_float(c), v);
    } else {
        const float* w = weight + (long long)c * FEAT;
        #pragma unroll
        for (int f = 0; f < FEAT; ++f)
            atomicAdd(out + (long long)r * FEAT + f, v * w[f]);
    }
}

__global__ __launch_bounds__(256) void gnn_gather(
    const float2* __restrict__ bins,
    const int* __restrict__ cnt,
    const float* __restrict__ weight,
    float* __restrict__ out,
    int n_nodes, int cap) {
    int g = (blockIdx.x * blockDim.x + threadIdx.x) >> 5;
    int f = threadIdx.x & (FEAT - 1);
    if (g >= n_nodes) return;
    int n = cnt[g];
    n = n < cap ? n : cap;
    const float2* b = bins + (long long)g * cap;
    float a0 = 0.f, a1 = 0.f, a2 = 0.f, a3 = 0.f;
    int j = 0;
    for (; j + 4 <= n; j += 4) {
        float2 e0 = b[j], e1 = b[j + 1], e2 = b[j + 2], e3 = b[j + 3];
        a0 += e0.y * weight[(long long)__float_as_int(e0.x) * FEAT + f];
        a1 += e1.y * weight[(long long)__float_as_int(e1.x) * FEAT + f];
        a2 += e2.y * weight[(long long)__float_as_int(e2.x) * FEAT + f];
        a3 += e3.y * weight[(long long)__float_as_int(e3.x) * FEAT + f];
    }
    for (; j < n; ++j) {
        float2 e0 = b[j];
        a0 += e0.y * weight[(long long)__float_as_int(e0.x) * FEAT + f];
    }
    out[(long long)g * FEAT + f] += (a0 + a1) + (a2 + a3);
}

// ---------------- v0 fallback ----------------

__global__ __launch_bounds__(256) void gnn_init_out(
    const float* __restrict__ bias, float* __restrict__ out, int total) {
    int i = blockIdx.x * blockDim.x + threadIdx.x;
    if (i < total) out[i] = bias[i & (FEAT - 1)];
}

__global__ __launch_bounds__(256) void gnn_scatter(
    const int* __restrict__ edge_row,
    const int* __restrict__ edge_col,
    const float* __restrict__ edge_val,
    const float* __restrict__ weight,
    float* __restrict__ out,
    int num_edges) {
    long long t = (long long)blockIdx.x * blockDim.x + threadIdx.x;
    int e = (int)(t >> 5);
    int f = (int)(t & (FEAT - 1));
    if (e < num_edges) {
        int r = edge_row[e];
        int c = edge_col[e];
        atomicAdd(out + r * FEAT + f, edge_val[e] * weight[c * FEAT + f]);
    }
}

extern "C" void kernel_launch(void* const* d_in, const int* in_sizes, int n_in,
                              void* d_out, int out_size, void* d_ws, size_t ws_size,
                              hipStream_t stream) {
    const int*   edge_row = (const int*)d_in[0];
    const int*   edge_col = (const int*)d_in[1];
    const float* edge_val = (const float*)d_in[2];
    const float* weight   = (const float*)d_in[3];
    const float* bias     = (const float*)d_in[4];
    float* out = (float*)d_out;

    const int E = in_sizes[0];
    const int total = out_size;        // N * 32 elements
    const int N = total / FEAT;
    const int B = (N + RPB - 1) >> LOG_RPB;

    auto align256 = [](size_t x) { return (x + 255) & ~(size_t)255; };
    size_t cursor_off = 0;
    size_t scnt_off   = align256(cursor_off + (size_t)B * sizeof(int));
    size_t spill_off  = align256(scnt_off + sizeof(int));
    size_t parts_off  = align256(spill_off + (size_t)E * sizeof(float4));
    size_t need_v13   = parts_off + (size_t)B * CAPB * sizeof(float2);

    if (B >= 1 && B <= BMAX && N <= (1 << COLBITS) && E > 0 && ws_size >= need_v13) {
        int*    cursor = (int*)((char*)d_ws + cursor_off);
        int*    scnt   = (int*)((char*)d_ws + scnt_off);
        float4* spill  = (float4*)((char*)d_ws + spill_off);
        float2* parts  = (float2*)((char*)d_ws + parts_off);

        gnn_zero<<<(B + 1 + 255) / 256, 256, 0, stream>>>(cursor, scnt, B);
        gnn_part<<<(E + PCHUNK - 1) / PCHUNK, PTHREADS, 0, stream>>>(
            edge_row, edge_col, edge_val, cursor, parts, spill, scnt, E, B);
        gnn_accum<<<B, 512, 0, stream>>>(
            parts, cursor, scnt, spill, weight, bias, out, N);
        return;
    }

    // v2 fallback: bin + gather
    size_t cnt_bytes = align256((size_t)N * sizeof(int));
    long long cap_ll = 0;
    if (ws_size > cnt_bytes)
        cap_ll = (long long)((ws_size - cnt_bytes) / ((size_t)N * sizeof(float2)));
    int cap = (int)(cap_ll > CAP_MAX ? CAP_MAX : cap_ll);

    if (cap >= 16) {
        int* cnt = (int*)d_ws;
        float2* bins = (float2*)((char*)d_ws + cnt_bytes);
        int total4 = total / 4;
        int init_threads = total4 > N ? total4 : N;
        gnn_init<<<(init_threads + 255) / 256, 256, 0, stream>>>(
            bias, out, cnt, total4, N);
        gnn_bin<<<(E + 255) / 256, 256, 0, stream>>>(
            edge_row, edge_col, edge_val, weight, bins, cnt, out, E, cap);
        long long gthreads = (long long)N * FEAT;
        gnn_gather<<<(int)((gthreads + 255) / 256), 256, 0, stream>>>(
            bins, cnt, weight, out, N, cap);
    } else {
        gnn_init_out<<<(total + 255) / 256, 256, 0, stream>>>(bias, out, total);
        long long threads = (long long)E * FEAT;
        gnn_scatter<<<(int)((threads + 255) / 256), 256, 0, stream>>>(
            edge_row, edge_col, edge_val, weight, out, E);
    }
}